// Round 10
// baseline (187.532 us; speedup 1.0000x reference)
//
#include <hip/hip_runtime.h>
#include <hip/hip_cooperative_groups.h>
#include <stdint.h>

namespace cg = cooperative_groups;

// Cooperative single-kernel HashGrid encoder + 32->128(relu)->64 MLP.
//
// Sub-phases separated by grid.sync() (one kernel = zero inter-pass launch
// overhead + full counter visibility):
//   sp0 : easy gather (levels 0..4 from fp32 tables, L2-resident everywhere)
//         + hard-table fp32->bf16 conversion + weight fragment packing.
//   sp1 : hard gather slice 0, ALL blocks (XCD-phased runs).
//   sp2-4: ROLE SPLIT — 9/16 of blocks gather slice s (XCD-phased, L2-
//         resident tables, transaction/latency-bound) CONCURRENT with 7/16
//         of blocks running the MFMA MLP on slice s-1 (HBM-write-bound).
//         Complementary resources -> overlap; worst case ~serial.
//   sp5 : MLP slice 3, ALL blocks.
//
// MLP math identical to R4-R9 (verified absmax 9.54e-7): both GEMMs
// transposed, shared k-map kappa(g,j)=16*(j>>2)+4g+(j&3) so layer-1's C
// fragment feeds layer-2's B fragment in-register; obuf LDS transpose so
// each out store covers a contiguous 1 KB (plain stores).

typedef __attribute__((ext_vector_type(8))) __bf16 bf16x8;
typedef __attribute__((ext_vector_type(4))) float  f32x4;
typedef __attribute__((ext_vector_type(2))) float  f32x2;

#define NPTS        1048576
#define NTILES      65536
#define SLICE_PTS   262144
#define SLICE_TILES 16384
#define XCD_CHUNKS  352      // (11 levels * 256 chunks) / 8 XCDs per slice

__device__ const unsigned kRES[16] = {16u,22u,30u,42u,58u,80u,111u,153u,
                                      212u,294u,406u,561u,776u,1072u,1482u,2048u};

__device__ __forceinline__ unsigned pack_bf16(float x, float y) {
  __bf16 a = (__bf16)x, b = (__bf16)y;
  unsigned short ua, ub;
  __builtin_memcpy(&ua, &a, 2);
  __builtin_memcpy(&ub, &b, 2);
  return (unsigned)ua | ((unsigned)ub << 16);
}

__global__ __launch_bounds__(256) void mega_kernel(
    const float* __restrict__ coords, const float* __restrict__ tables,
    const float* __restrict__ W1, const float* __restrict__ b1,
    const float* __restrict__ W2, const float* __restrict__ b2,
    unsigned* __restrict__ tb2, unsigned* __restrict__ xw,
    short* __restrict__ w1p, short* __restrict__ w2p,
    float* __restrict__ out, int nper, int ng)
{
  cg::grid_group grid = cg::this_grid();
  const int tid = threadIdx.x;
  const int l = tid & 63;
  const int g = l >> 4;
  const int c = l & 15;
  const int w = tid >> 6;
  const int b = blockIdx.x;
  const int x = b & 7;        // assumed XCD (perf heuristic only)
  const int r = b >> 3;       // rank within XCD
  const int B = gridDim.x;

  __shared__ float obuf[4][16][68];

  // ---------------- sp0: easy gather + tconv + wprep ----------------
  for (int u = b; u < 6662; u += B) {
    if (u < 1024) {
      // easy levels 0..4 straight from fp32 tables (bit-identical cast)
      int p0 = u * 1024 + tid;
#pragma unroll
      for (int i = 0; i < 4; ++i) {
        int p = p0 + (i << 8);
        float u0 = (coords[3*p+0] + 1.0f) * 0.5f;
        float u1 = (coords[3*p+1] + 1.0f) * 0.5f;
        float u2 = (coords[3*p+2] + 1.0f) * 0.5f;
#pragma unroll
        for (int lv = 0; lv < 5; ++lv) {
          const unsigned R = kRES[lv];
          const unsigned Rm1 = R - 1u;
          unsigned d0 = (unsigned)(int)(u0 * (float)R); if (d0 > Rm1) d0 = Rm1;
          unsigned d1 = (unsigned)(int)(u1 * (float)R); if (d1 > Rm1) d1 = Rm1;
          unsigned d2 = (unsigned)(int)(u2 * (float)R); if (d2 > Rm1) d2 = Rm1;
          unsigned idx = d0*(R*R) + d1*R + d2;   // < R^3 = T
          f32x2 f = *(const f32x2*)(tables + ((size_t)lv << 20) + (size_t)idx*2u);
          xw[((size_t)lv << 20) + p] = pack_bf16(f.x, f.y);
        }
      }
    } else if (u < 6656) {
      // convert hard levels 5..15 fp32x2 -> bf16x2
      int e0 = 5*524288 + (u - 1024) * 1024 + tid * 4;
#pragma unroll
      for (int i = 0; i < 4; ++i) {
        int e = e0 + i;
        f32x2 f = *(const f32x2*)(tables + (size_t)e * 2);
        tb2[e] = pack_bf16(f.x, f.y);
      }
    } else {
      // weight fragment packing (shared k-map)
      int t2 = (u - 6656) * 256 + tid;   // 0..1535
      if (t2 < 512) {
        int t = t2 >> 6;
        bf16x8 v;
#pragma unroll
        for (int j = 0; j < 8; ++j)
          v[j] = (__bf16)W1[(8*g + j)*128 + 16*t + c];
        *(bf16x8*)(w1p + (size_t)(t*64 + l)*8) = v;
      } else if (t2 < 1536) {
        int e = (t2 - 512) >> 6;
        int mt = e >> 2, ks = e & 3;
        bf16x8 v;
#pragma unroll
        for (int j = 0; j < 8; ++j)
          v[j] = (__bf16)W2[(32*ks + 16*(j>>2) + 4*g + (j&3))*64 + 16*mt + c];
        *(bf16x8*)(w2p + (size_t)(e*64 + l)*8) = v;
      }
    }
  }

  // ---- hard-gather for one slice: per-XCD contiguous 352-chunk run ----
  auto gather_slice = [&](int s, int rank, int stride) {
    for (int h = rank; h < XCD_CHUNKS; h += stride) {
      int hh = x * XCD_CHUNKS + h;           // 0..2815
      int lv = 5 + (hh >> 8);                // 5..15
      int ch = hh & 255;
      const unsigned R = kRES[lv];
      const float fR = (float)R;
      const unsigned RR = R * R;
      const unsigned Rm1 = R - 1u;
      // lv>=6: T=2^19 (mask); lv==5: 80^3 = T -> idx < T already.
      const unsigned M = (lv >= 6) ? 0x7FFFFu : 0xFFFFFFFFu;
      const unsigned* tb = tb2 + ((size_t)lv << 19);
      unsigned* xp = xw + ((size_t)lv << 20);
      int p0 = s * SLICE_PTS + ch * 1024 + tid;
#pragma unroll
      for (int i = 0; i < 4; ++i) {
        int p = p0 + (i << 8);
        float u0 = (coords[3*p+0] + 1.0f) * 0.5f;
        float u1 = (coords[3*p+1] + 1.0f) * 0.5f;
        float u2 = (coords[3*p+2] + 1.0f) * 0.5f;
        unsigned d0 = (unsigned)(int)(u0 * fR); if (d0 > Rm1) d0 = Rm1;
        unsigned d1 = (unsigned)(int)(u1 * fR); if (d1 > Rm1) d1 = Rm1;
        unsigned d2 = (unsigned)(int)(u2 * fR); if (d2 > Rm1) d2 = Rm1;
        // uint32 wraparound matches reference (T=2^19 divides 2^32)
        unsigned idx = (d0*RR + d1*R + d2) & M;
        xp[p] = tb[idx];
      }
    }
  };

  // ---- MLP over one slice, grid-stride by wave ----
  auto mlp_slice = [&](int s, int wid, int nwaves) {
    bf16x8 w1f[8];
#pragma unroll
    for (int t = 0; t < 8; ++t)
      w1f[t] = *(const bf16x8*)(w1p + (size_t)(t*64 + l)*8);

    const int end = (s + 1) * SLICE_TILES;
    int t = s * SLICE_TILES + wid;
    if (t >= end) return;
    unsigned gx[4];
#pragma unroll
    for (int q = 0; q < 4; ++q)
      gx[q] = xw[((size_t)(4*g + q) << 20) + t*16 + c];

    while (t < end) {
      int nt = t + nwaves;
      unsigned gx2[4];
      if (nt < end) {
#pragma unroll
        for (int q = 0; q < 4; ++q)
          gx2[q] = xw[((size_t)(4*g + q) << 20) + nt*16 + c];
      }
      union { bf16x8 v; unsigned u[4]; } X;
#pragma unroll
      for (int q = 0; q < 4; ++q) X.u[q] = gx[q];
      bf16x8 xf = X.v;

      f32x4 h[8];
#pragma unroll
      for (int tt = 0; tt < 8; ++tt) {
        h[tt] = *(const f32x4*)(b1 + 16*tt + 4*g);
        h[tt] = __builtin_amdgcn_mfma_f32_16x16x32_bf16(w1f[tt], xf, h[tt], 0, 0, 0);
      }
      f32x4 o[4];
#pragma unroll
      for (int mt = 0; mt < 4; ++mt)
        o[mt] = *(const f32x4*)(b2 + 16*mt + 4*g);
#pragma unroll
      for (int ks = 0; ks < 4; ++ks) {
        bf16x8 bp;
#pragma unroll
        for (int j = 0; j < 8; ++j) {
          float v = h[2*ks + (j>>2)][j & 3];
          v = fmaxf(v, 0.0f);               // fused ReLU
          bp[j] = (__bf16)v;
        }
#pragma unroll
        for (int mt = 0; mt < 4; ++mt) {
          bf16x8 w2f = *(const bf16x8*)(w2p + (size_t)((mt*4 + ks)*64 + l)*8);
          o[mt] = __builtin_amdgcn_mfma_f32_16x16x32_bf16(w2f, bp, o[mt], 0, 0, 0);
        }
      }
      // obuf LDS transpose -> contiguous 1 KB per store instruction
      float (*ob)[68] = obuf[w];
#pragma unroll
      for (int mt = 0; mt < 4; ++mt)
        *(f32x4*)&ob[c][16*mt + 4*g] = o[mt];
      asm volatile("s_waitcnt lgkmcnt(0)" ::: "memory");
      f32x4 v[4];
#pragma unroll
      for (int sdx = 0; sdx < 4; ++sdx)
        v[sdx] = *(const f32x4*)&ob[4*sdx + g][4*c];
      asm volatile("" ::: "memory");
      float* op = out + (size_t)t * 1024;
#pragma unroll
      for (int sdx = 0; sdx < 4; ++sdx)
        *(f32x4*)(op + (4*sdx + g)*64 + 4*c) = v[sdx];
      asm volatile("s_waitcnt lgkmcnt(0)" ::: "memory");
#pragma unroll
      for (int q = 0; q < 4; ++q) gx[q] = gx2[q];
      t = nt;
    }
  };

  __threadfence();
  grid.sync();

  // ---------------- sp1: gather slice 0, ALL blocks ----------------
  gather_slice(0, r, nper);
  __threadfence();
  grid.sync();

  // ---------------- sp2..4: gather slice s-1 || mlp slice s-2 ----------
  const int nm = nper - ng;
  for (int s = 2; s <= 4; ++s) {
    if (r < ng) gather_slice(s - 1, r, ng);
    else        mlp_slice(s - 2, ((r - ng)*8 + x)*4 + w, 4*8*nm);
    __threadfence();
    grid.sync();
  }
  // ---------------- sp5: mlp slice 3, ALL blocks ----------------
  mlp_slice(3, (r*8 + x)*4 + w, 4*B);
}

// =================== fallback: R9 three-kernel path ===================
__global__ __launch_bounds__(256) void tconv_prep_kernel(
    const float* __restrict__ coords, const float* __restrict__ tables,
    const float* __restrict__ W1, const float* __restrict__ W2,
    unsigned* __restrict__ tb2, unsigned* __restrict__ xw,
    short* __restrict__ w1p, short* __restrict__ w2p)
{
  const int l = threadIdx.x & 63;
  const int g = l >> 4;
  const int c = l & 15;
  if (blockIdx.x < 1024) {
    int p0 = blockIdx.x * 1024 + threadIdx.x;
#pragma unroll
    for (int i = 0; i < 4; ++i) {
      int p = p0 + (i << 8);
      float u0 = (coords[3*p+0] + 1.0f) * 0.5f;
      float u1 = (coords[3*p+1] + 1.0f) * 0.5f;
      float u2 = (coords[3*p+2] + 1.0f) * 0.5f;
#pragma unroll
      for (int lv = 0; lv < 5; ++lv) {
        const unsigned R = kRES[lv];
        const unsigned Rm1 = R - 1u;
        unsigned d0 = (unsigned)(int)(u0 * (float)R); if (d0 > Rm1) d0 = Rm1;
        unsigned d1 = (unsigned)(int)(u1 * (float)R); if (d1 > Rm1) d1 = Rm1;
        unsigned d2 = (unsigned)(int)(u2 * (float)R); if (d2 > Rm1) d2 = Rm1;
        unsigned idx = d0*(R*R) + d1*R + d2;
        f32x2 f = *(const f32x2*)(tables + ((size_t)lv << 20) + (size_t)idx*2u);
        xw[((size_t)lv << 20) + p] = pack_bf16(f.x, f.y);
      }
    }
    return;
  }
  if (blockIdx.x < 6656) {
    int e0 = 5*524288 + ((int)(blockIdx.x - 1024) * 256 + (int)threadIdx.x) * 4;
#pragma unroll
    for (int i = 0; i < 4; ++i) {
      int e = e0 + i;
      f32x2 f = *(const f32x2*)(tables + (size_t)e * 2);
      tb2[e] = pack_bf16(f.x, f.y);
    }
    return;
  }
  int tid = (blockIdx.x - 6656) * 256 + threadIdx.x;
  if (tid < 512) {
    int t = tid >> 6;
    bf16x8 v;
#pragma unroll
    for (int j = 0; j < 8; ++j)
      v[j] = (__bf16)W1[(8*g + j)*128 + 16*t + c];
    *(bf16x8*)(w1p + (size_t)(t*64 + l)*8) = v;
  } else if (tid < 1536) {
    int e = (tid - 512) >> 6;
    int mt = e >> 2, ks = e & 3;
    bf16x8 v;
#pragma unroll
    for (int j = 0; j < 8; ++j)
      v[j] = (__bf16)W2[(32*ks + 16*(j>>2) + 4*g + (j&3))*64 + 16*mt + c];
    *(bf16x8*)(w2p + (size_t)(e*64 + l)*8) = v;
  }
}

__global__ __launch_bounds__(256) void gather_kernel(
    const float* __restrict__ coords, const unsigned* __restrict__ tb2,
    unsigned* __restrict__ xw)
{
  const int xcd = blockIdx.x & 7;
  const int j   = blockIdx.x >> 3;
  int ghi = xcd * 1408 + j;
  int lv = 5 + (ghi >> 10);
  int chunk = ghi & 1023;
  const unsigned R = kRES[lv];
  const float fR = (float)R;
  const unsigned RR = R * R;
  const unsigned Rm1 = R - 1u;
  const unsigned M = (lv >= 6) ? 0x7FFFFu : 0xFFFFFFFFu;
  const unsigned* tb = tb2 + ((size_t)lv << 19);
  unsigned* xp = xw + ((size_t)lv << 20);
  int p0 = chunk * 1024 + threadIdx.x;
#pragma unroll
  for (int i = 0; i < 4; ++i) {
    int p = p0 + (i << 8);
    float u0 = (coords[3*p+0] + 1.0f) * 0.5f;
    float u1 = (coords[3*p+1] + 1.0f) * 0.5f;
    float u2 = (coords[3*p+2] + 1.0f) * 0.5f;
    unsigned d0 = (unsigned)(int)(u0 * fR); if (d0 > Rm1) d0 = Rm1;
    unsigned d1 = (unsigned)(int)(u1 * fR); if (d1 > Rm1) d1 = Rm1;
    unsigned d2 = (unsigned)(int)(u2 * fR); if (d2 > Rm1) d2 = Rm1;
    unsigned idx = (d0*RR + d1*R + d2) & M;
    xp[p] = tb[idx];
  }
}

__global__ __launch_bounds__(256, 4) void mlp_kernel(
    const unsigned* __restrict__ xw,
    const float* __restrict__ b1, const float* __restrict__ b2,
    const short* __restrict__ w1p, const short* __restrict__ w2p,
    float* __restrict__ out)
{
  const int l = threadIdx.x & 63;
  const int g = l >> 4;
  const int c = l & 15;
  const int w = threadIdx.x >> 6;
  __shared__ float obuf[4][16][68];
  bf16x8 w1f[8];
#pragma unroll
  for (int t = 0; t < 8; ++t)
    w1f[t] = *(const bf16x8*)(w1p + (size_t)(t*64 + l)*8);
  const int base = blockIdx.x * 4 + w;
  unsigned gx[2][4];
#pragma unroll
  for (int it = 0; it < 2; ++it) {
    int p = (base + it*32768)*16 + c;
#pragma unroll
    for (int q = 0; q < 4; ++q)
      gx[it][q] = xw[((size_t)(4*g + q) << 20) + p];
  }
#pragma unroll
  for (int it = 0; it < 2; ++it) {
    union { bf16x8 v; unsigned u[4]; } X;
#pragma unroll
    for (int q = 0; q < 4; ++q) X.u[q] = gx[it][q];
    bf16x8 xf = X.v;
    f32x4 h[8];
#pragma unroll
    for (int t = 0; t < 8; ++t) {
      h[t] = *(const f32x4*)(b1 + 16*t + 4*g);
      h[t] = __builtin_amdgcn_mfma_f32_16x16x32_bf16(w1f[t], xf, h[t], 0, 0, 0);
    }
    f32x4 o[4];
#pragma unroll
    for (int mt = 0; mt < 4; ++mt)
      o[mt] = *(const f32x4*)(b2 + 16*mt + 4*g);
#pragma unroll
    for (int ks = 0; ks < 4; ++ks) {
      bf16x8 bp;
#pragma unroll
      for (int j = 0; j < 8; ++j) {
        float v = h[2*ks + (j>>2)][j & 3];
        v = fmaxf(v, 0.0f);
        bp[j] = (__bf16)v;
      }
#pragma unroll
      for (int mt = 0; mt < 4; ++mt) {
        bf16x8 w2f = *(const bf16x8*)(w2p + (size_t)((mt*4 + ks)*64 + l)*8);
        o[mt] = __builtin_amdgcn_mfma_f32_16x16x32_bf16(w2f, bp, o[mt], 0, 0, 0);
      }
    }
    float (*ob)[68] = obuf[w];
#pragma unroll
    for (int mt = 0; mt < 4; ++mt)
      *(f32x4*)&ob[c][16*mt + 4*g] = o[mt];
    asm volatile("s_waitcnt lgkmcnt(0)" ::: "memory");
    f32x4 v[4];
#pragma unroll
    for (int s = 0; s < 4; ++s)
      v[s] = *(const f32x4*)&ob[4*s + g][4*c];
    asm volatile("" ::: "memory");
    float* op = out + (size_t)(base + it*32768) * 1024;
#pragma unroll
    for (int s = 0; s < 4; ++s)
      *(f32x4*)(op + (4*s + g)*64 + 4*c) = v[s];
    if (it < 1) asm volatile("s_waitcnt lgkmcnt(0)" ::: "memory");
  }
}

extern "C" void kernel_launch(void* const* d_in, const int* in_sizes, int n_in,
                              void* d_out, int out_size, void* d_ws, size_t ws_size,
                              hipStream_t stream) {
  const float* coords = (const float*)d_in[0];
  const float* tables = (const float*)d_in[1];
  const float* W1     = (const float*)d_in[2];
  const float* b1     = (const float*)d_in[3];
  const float* W2     = (const float*)d_in[4];
  const float* b2     = (const float*)d_in[5];
  float* out = (float*)d_out;

  short* w1p = (short*)d_ws;                       // 8 KB
  short* w2p = w1p + 4096;                         // 16 KB (ends 24 KB)

  const size_t XW_OFF  = 32*1024;
  const size_t XW_SZ   = (size_t)NPTS * 16 * 4;    // 64 MB
  const size_t TB2_SZ  = (size_t)16 * 524288 * 4;  // 32 MB
  unsigned* xw  = (unsigned*)((char*)d_ws + XW_OFF);
  unsigned* tb2 = (unsigned*)((char*)d_ws + XW_OFF + XW_SZ);

  // cooperative capability + occupancy (host-only queries: capture-safe,
  // deterministic across calls)
  int dev = 0; hipGetDevice(&dev);
  int coop = 0;
  hipDeviceGetAttribute(&coop, hipDeviceAttributeCooperativeLaunch, dev);
  int maxb = 0;
  hipOccupancyMaxActiveBlocksPerMultiprocessor(&maxb, (const void*)mega_kernel, 256, 0);

  if (ws_size >= XW_OFF + XW_SZ + TB2_SZ && coop && maxb > 0) {
    if (maxb > 8) maxb = 8;
    int B = maxb * 256;                 // 256 CUs; multiple of 8
    if (B > 2048) B = 2048;
    int nper = B / 8;                   // blocks per XCD
    int ng = (9 * nper) / 16;           // gather-role blocks per XCD
    if (ng < 1) ng = 1;
    if (ng > nper - 1) ng = nper - 1;
    void* args[] = {(void*)&coords, (void*)&tables, (void*)&W1, (void*)&b1,
                    (void*)&W2, (void*)&b2, (void*)&tb2, (void*)&xw,
                    (void*)&w1p, (void*)&w2p, (void*)&out,
                    (void*)&nper, (void*)&ng};
    hipLaunchCooperativeKernel((void*)mega_kernel, dim3(B), dim3(256),
                               args, 0, stream);
  } else if (ws_size >= XW_OFF + XW_SZ + TB2_SZ) {
    tconv_prep_kernel<<<6662, 256, 0, stream>>>(coords, tables, W1, W2,
                                                tb2, xw, w1p, w2p);
    gather_kernel<<<11264, 256, 0, stream>>>(coords, tb2, xw);
    mlp_kernel<<<8192, 256, 0, stream>>>(xw, b1, b2, w1p, w2p, out);
  }
}